// Round 3
// baseline (171.878 us; speedup 1.0000x reference)
//
#include <hip/hip_runtime.h>
#include <stdint.h>

// set attention: N=32, L=256, D=20, H=2, Dh=20, fp32 I/O.
// Out batch b: Q from x[b], K/V from y[(b&31)*32 + (b>>5)].
// R7: occupancy-only change vs R0-proven kernel; ALL arithmetic primitives R0-exact.
//   - Heads sequential -> per-head sK/sVt; Q/O via per-wave scratch transpose.
//   - LDS 36.2 KB -> 4 blocks/CU (vs R0's 71.7 KB / 2 blocks).
//   - Every LDS write->read transition is a __syncthreads().
//   - Conversions: R0 bit-math RNE (v_cvt_pk_bf16_f32 convicted in R1/R2 NaNs).

#define NSET 32
#define SEQL 256
#define DM   20
#define NH   2
#define DH   20

typedef __attribute__((ext_vector_type(8))) short short8;
typedef __attribute__((ext_vector_type(4))) short short4v;
typedef __attribute__((ext_vector_type(4))) float f32x4;

#define MFMA32(a, b, c) __builtin_amdgcn_mfma_f32_16x16x32_bf16((a), (b), (c), 0, 0, 0)

#if __has_builtin(__builtin_amdgcn_mfma_f32_16x16x16bf16_1k)
#define MFMA16(a, b, c) __builtin_amdgcn_mfma_f32_16x16x16bf16_1k((a), (b), (c), 0, 0, 0)
#elif __has_builtin(__builtin_amdgcn_mfma_f32_16x16x16_bf16)
#define MFMA16(a, b, c) __builtin_amdgcn_mfma_f32_16x16x16_bf16((a), (b), (c), 0, 0, 0)
#else
static __device__ __forceinline__ f32x4 MFMA16(short4v a, short4v b, f32x4 c) {
    asm volatile("s_nop 1\n\tv_mfma_f32_16x16x16_bf16 %0, %1, %2, %0\n\ts_nop 7"
                 : "+v"(c) : "v"(a), "v"(b));
    return c;
}
#endif

__device__ __forceinline__ uint32_t bfbits_rne(float f) {
    uint32_t u = __float_as_uint(f);
    return ((u + 0x7fffu + ((u >> 16) & 1u)) >> 16) & 0xffffu;
}
__device__ __forceinline__ float fexp2(float x) {
    float r;
    asm("v_exp_f32 %0, %1" : "=v"(r) : "v"(x));
    return r;
}

// predicated b128 A/B-frag load from row-major [rows][24] bf16 region
__device__ __forceinline__ short8 ldsA(const short* base, int row, int qd) {
    short8 f = {0, 0, 0, 0, 0, 0, 0, 0};
    if (qd < 3) f = *(const short8*)(base + row * 24 + qd * 8);
    return f;
}

// global fp32 row (20 floats, 16B-aligned) -> bf16 frag for k-quad qd (R0-exact)
__device__ __forceinline__ short8 gfrag(const float* rowp, int qd) {
    short8 f = {0, 0, 0, 0, 0, 0, 0, 0};
    if (qd < 2) {
        float4 a = *(const float4*)(rowp + qd * 8);
        float4 b = *(const float4*)(rowp + qd * 8 + 4);
        f[0] = (short)bfbits_rne(a.x); f[1] = (short)bfbits_rne(a.y);
        f[2] = (short)bfbits_rne(a.z); f[3] = (short)bfbits_rne(a.w);
        f[4] = (short)bfbits_rne(b.x); f[5] = (short)bfbits_rne(b.y);
        f[6] = (short)bfbits_rne(b.z); f[7] = (short)bfbits_rne(b.w);
    } else if (qd == 2) {
        float4 a = *(const float4*)(rowp + 16);
        f[0] = (short)bfbits_rne(a.x); f[1] = (short)bfbits_rne(a.y);
        f[2] = (short)bfbits_rne(a.z); f[3] = (short)bfbits_rne(a.w);
    }
    return f;
}

__global__ __launch_bounds__(256, 4) void set_attn_v7(
    const float* __restrict__ x, const float* __restrict__ y,
    const float* __restrict__ wq, const float* __restrict__ wk,
    const float* __restrict__ wv, const float* __restrict__ wh,
    float* __restrict__ out)
{
    __shared__ __align__(16) short sK[SEQL * 24];     // per-head K, 12 KB
    __shared__ __align__(16) short sVt[20 * 264];     // per-head V^T [d][s], 10.3 KB
    __shared__ __align__(16) short sW[4 * 64 * 24];   // per-wave transpose scratch, 12 KB
    __shared__ float sL[256];                         // per-row softmax denom, 1 KB

    const int tid  = threadIdx.x;
    const int lane = tid & 63;
    const int w    = tid >> 6;
    const int c    = lane & 15;
    const int qd   = lane >> 4;
    const int b    = blockIdx.x;
    const int bi   = b >> 5, bj = b & 31;

    short* myW = sW + w * (64 * 24);

    // zero pad cols 20..23 (read by qd==2 frags); later writes never touch them
    *(uint2*)(sK + tid * 24 + 20) = make_uint2(0u, 0u);
    *(uint2*)(myW + lane * 24 + 20) = make_uint2(0u, 0u);

    const float QS = 0.22360679774997896f * 1.4426950408889634f;  // scale * log2(e)

    // ---- Q projection (both heads), barrier-synced scratch transpose ----
    short8 xf[4];
#pragma unroll
    for (int mt = 0; mt < 4; ++mt)
        xf[mt] = gfrag(x + ((size_t)b * SEQL + w * 64 + mt * 16 + c) * DM, qd);

    short8 qb[2][4];
#pragma unroll
    for (int h = 0; h < 2; ++h) {
        short8 wqf[2];
#pragma unroll
        for (int dt = 0; dt < 2; ++dt) {
            int n = dt * 16 + c;
            short8 f = {0,0,0,0,0,0,0,0};
            if (n < 20) {
#pragma unroll
                for (int j = 0; j < 8; ++j) {
                    int k = qd * 8 + j;
                    if (k < 20) f[j] = (short)bfbits_rne(wq[k * 40 + h * 20 + n]);
                }
            }
            wqf[dt] = f;
        }
#pragma unroll
        for (int mt = 0; mt < 4; ++mt) {
#pragma unroll
            for (int dt = 0; dt < 2; ++dt) {
                f32x4 z = {0.f, 0.f, 0.f, 0.f};
                f32x4 qres = MFMA32(xf[mt], wqf[dt], z);
                int n = dt * 16 + c;
                if (n < 20) {
#pragma unroll
                    for (int reg = 0; reg < 4; ++reg)
                        myW[(mt * 16 + qd * 4 + reg) * 24 + n] =
                            (short)bfbits_rne(qres[reg] * QS);
                }
            }
        }
        __syncthreads();   // Q writes (and pads, first iter) visible
#pragma unroll
        for (int mt = 0; mt < 4; ++mt) qb[h][mt] = ldsA(myW, mt * 16 + c, qd);
        __syncthreads();   // reads retired before scratch overwritten
    }

    // ---- K/V projection for head h into sK / sVt (R0-exact arithmetic) ----
    auto project_kv = [&](int h) {
        short8 wkf[2], wvf[2];
#pragma unroll
        for (int dt = 0; dt < 2; ++dt) {
            int n = dt * 16 + c;
            short8 fk = {0,0,0,0,0,0,0,0}, fv = fk;
            if (n < 20) {
#pragma unroll
                for (int j = 0; j < 8; ++j) {
                    int k = qd * 8 + j;
                    if (k < 20) {
                        fk[j] = (short)bfbits_rne(wk[k * 40 + h * 20 + n]);
                        fv[j] = (short)bfbits_rne(wv[k * 40 + h * 20 + n]);
                    }
                }
            }
            wkf[dt] = fk; wvf[dt] = fv;
        }
#pragma unroll
        for (int mt = 0; mt < 4; ++mt) {
            int rbase = w * 64 + mt * 16;
            short8 yf = gfrag(y + ((size_t)(bj * NSET + bi) * SEQL + rbase + c) * DM, qd);
#pragma unroll
            for (int dt = 0; dt < 2; ++dt) {
                f32x4 z = {0.f, 0.f, 0.f, 0.f};
                f32x4 kres = MFMA32(yf, wkf[dt], z);
                f32x4 vres = MFMA32(yf, wvf[dt], z);
                int n = dt * 16 + c;
                if (n < 20) {
#pragma unroll
                    for (int reg = 0; reg < 4; ++reg) {
                        int row = rbase + qd * 4 + reg;
                        sK[row * 24 + n] = (short)bfbits_rne(kres[reg]);
                        sVt[n * 264 + row] = (short)bfbits_rne(vres[reg]);
                    }
                }
            }
        }
    };

    project_kv(0);
    __syncthreads();   // B1: sK/sVt head0 ready

    f32x4 outacc[4][2];
#pragma unroll
    for (int mt = 0; mt < 4; ++mt)
#pragma unroll
        for (int dt = 0; dt < 2; ++dt) outacc[mt][dt] = (f32x4){0.f, 0.f, 0.f, 0.f};

#pragma unroll
    for (int h = 0; h < NH; ++h) {
        f32x4 oacc[4][2];
#pragma unroll
        for (int mt = 0; mt < 4; ++mt)
#pragma unroll
            for (int dt = 0; dt < 2; ++dt) oacc[mt][dt] = (f32x4){0.f, 0.f, 0.f, 0.f};
        float ls0 = 0.f, ls1 = 0.f, ls2 = 0.f, ls3 = 0.f;

        for (int s0 = 0; s0 < SEQL; s0 += 32) {
            short8 kf0 = ldsA(sK, s0 + c, qd);
            short8 kf1 = ldsA(sK, s0 + 16 + c, qd);
            short4v vb[2][2];
#pragma unroll
            for (int dt = 0; dt < 2; ++dt) {
                int d = dt * 16 + c;
#pragma unroll
                for (int st = 0; st < 2; ++st) {
                    uint2 u = make_uint2(0u, 0u);
                    if (d < 20)
                        u = *(const uint2*)(sVt + d * 264 + s0 + st * 16 + qd * 4);
                    short4v t; *(uint2*)&t = u;
                    vb[st][dt] = t;
                }
            }
#pragma unroll
            for (int mt = 0; mt < 4; ++mt) {
#pragma unroll
                for (int st = 0; st < 2; ++st) {
                    f32x4 z = {0.f, 0.f, 0.f, 0.f};
                    f32x4 sacc = MFMA32((st == 0 ? kf0 : kf1), qb[h][mt], z);
                    float p0, p1, p2, p3;
                    {
                        float v0 = sacc[0], v1 = sacc[1], v2 = sacc[2], v3 = sacc[3];
                        p0 = (v0 != 0.f) ? fexp2(v0) : 0.f;   // zero-logit mask
                        p1 = (v1 != 0.f) ? fexp2(v1) : 0.f;
                        p2 = (v2 != 0.f) ? fexp2(v2) : 0.f;
                        p3 = (v3 != 0.f) ? fexp2(v3) : 0.f;
                    }
                    float lsum = (p0 + p1) + (p2 + p3);
                    if (mt == 0) ls0 += lsum;
                    else if (mt == 1) ls1 += lsum;
                    else if (mt == 2) ls2 += lsum;
                    else ls3 += lsum;
                    short4v pf;
                    *(uint2*)&pf = make_uint2(bfbits_rne(p0) | (bfbits_rne(p1) << 16),
                                              bfbits_rne(p2) | (bfbits_rne(p3) << 16));
                    oacc[mt][0] = MFMA16(pf, vb[st][0], oacc[mt][0]);
                    oacc[mt][1] = MFMA16(pf, vb[st][1], oacc[mt][1]);
                }
            }
        }

        // ---- softmax denominators: reduce over qd groups, broadcast via sL ----
        ls0 += __shfl_xor(ls0, 16, 64); ls0 += __shfl_xor(ls0, 32, 64);
        ls1 += __shfl_xor(ls1, 16, 64); ls1 += __shfl_xor(ls1, 32, 64);
        ls2 += __shfl_xor(ls2, 16, 64); ls2 += __shfl_xor(ls2, 32, 64);
        ls3 += __shfl_xor(ls3, 16, 64); ls3 += __shfl_xor(ls3, 32, 64);
        float sel = ls0;
        if (qd == 1) sel = ls1;
        if (qd == 2) sel = ls2;
        if (qd == 3) sel = ls3;
        sL[w * 64 + lane] = sel;   // sL[w*64 + i] = denom of wave-local row i
        __syncthreads();           // sL visible

        // ---- normalize O into wave scratch ----
        short8 whf[2];
#pragma unroll
        for (int dt = 0; dt < 2; ++dt) {
            int n = dt * 16 + c;
            short8 f = {0,0,0,0,0,0,0,0};
            if (n < 20) {
#pragma unroll
                for (int j = 0; j < 8; ++j) {
                    int k = qd * 8 + j;
                    if (k < 20) f[j] = (short)bfbits_rne(wh[(h * 20 + k) * 20 + n]);
                }
            }
            whf[dt] = f;
        }
#pragma unroll
        for (int mt = 0; mt < 4; ++mt) {
            float inv[4];
#pragma unroll
            for (int reg = 0; reg < 4; ++reg)
                inv[reg] = 1.f / (sL[w * 64 + mt * 16 + qd * 4 + reg] + 1e-10f);
#pragma unroll
            for (int dt = 0; dt < 2; ++dt) {
                int n = dt * 16 + c;
                if (n < 20) {
#pragma unroll
                    for (int reg = 0; reg < 4; ++reg)
                        myW[(mt * 16 + qd * 4 + reg) * 24 + n] =
                            (short)bfbits_rne(oacc[mt][dt][reg] * inv[reg]);
                }
            }
        }
        __syncthreads();   // O writes visible before transposed read

        // ---- out-projection: outacc += O_h * WH[h*20:(h+1)*20, :] ----
#pragma unroll
        for (int mt = 0; mt < 4; ++mt) {
            short8 of = ldsA(myW, mt * 16 + c, qd);
            outacc[mt][0] = MFMA32(of, whf[0], outacc[mt][0]);
            outacc[mt][1] = MFMA32(of, whf[1], outacc[mt][1]);
        }

        if (h == 0) {
            __syncthreads();     // B2: all reads of sK/sVt head0 + myW done
            project_kv(1);
            __syncthreads();     // B3: sK/sVt head1 ready
        }
    }

    // ---- store fp32 output ----
    float* ob = out + (size_t)b * (SEQL * DH);
#pragma unroll
    for (int mt = 0; mt < 4; ++mt)
#pragma unroll
        for (int dt = 0; dt < 2; ++dt) {
            int n = dt * 16 + c;
            if (n < 20) {
#pragma unroll
                for (int reg = 0; reg < 4; ++reg) {
                    int row = w * 64 + mt * 16 + qd * 4 + reg;
                    ob[row * 20 + n] = outacc[mt][dt][reg];
                }
            }
        }
}

extern "C" void kernel_launch(void* const* d_in, const int* in_sizes, int n_in,
                              void* d_out, int out_size, void* d_ws, size_t ws_size,
                              hipStream_t stream) {
    const float* x  = (const float*)d_in[0];
    const float* y  = (const float*)d_in[1];
    const float* wq = (const float*)d_in[2];
    const float* wk = (const float*)d_in[3];
    const float* wv = (const float*)d_in[4];
    const float* wh = (const float*)d_in[5];
    float* out = (float*)d_out;

    set_attn_v7<<<dim3(NSET * NSET), dim3(SEQL), 0, stream>>>(x, y, wq, wk, wv, wh, out);
}